// Round 4
// baseline (458.150 us; speedup 1.0000x reference)
//
#include <hip/hip_runtime.h>
#include <hip/hip_bf16.h>
#include <stdint.h>

#define QB 127.0f
#define EPS_G 1e-5f
#define KD 4096
#define ND 4096
#define BM 256
#define BN 256
#define BKB 128           // K-bytes (= i8 elements) per K-tile
#define NT (KD / BKB)     // 32 K-tiles
#define NI (NT / 2)       // 16 iterations, 2 K-tiles each

typedef int v4i __attribute__((ext_vector_type(4)));

#define GLOAD16(gp, lp)                                                        \
  __builtin_amdgcn_global_load_lds(                                            \
      (const __attribute__((address_space(1))) void*)(gp),                     \
      (__attribute__((address_space(3))) void*)(lp), 16, 0, 0)

#define BAR  __builtin_amdgcn_s_barrier()
#define SB0  __builtin_amdgcn_sched_barrier(0)
#define WLG0 asm volatile("s_waitcnt lgkmcnt(0)" ::: "memory")
#define WVM4 asm volatile("s_waitcnt vmcnt(4)" ::: "memory")

// Inline-asm LDS read: compiler sees only the register def (no LDS alias
// tracking -> no conservative auto-waitcnt vs in-flight global_load_lds).
// Correctness: WLG0 + SB0 before each consuming MFMA cluster (rule #18).
#define DSR(dst, addr)                                                         \
  asm volatile("ds_read_b128 %0, %1" : "=v"(dst) : "v"(addr))

// ---------------------------------------------------------------------------
// Fused quant: blocks [0,M) quantize x rows (absmax int8); blocks [M,M+N)
// convert w rows {-1,0,1} fp32 -> i8. One row of 4096 per 256-thread block.
// ---------------------------------------------------------------------------
__global__ __launch_bounds__(256) void quant_fused_kernel(
    const float* __restrict__ x, const float* __restrict__ w,
    signed char* __restrict__ xq, signed char* __restrict__ wq,
    float* __restrict__ gamma_out, int M) {
  const int b = blockIdx.x;
  const int t = threadIdx.x;
  if (b < M) {
    const float4* xr = (const float4*)(x + (size_t)b * KD);
    float4 v[4];
    float m = 0.f;
#pragma unroll
    for (int i = 0; i < 4; ++i) {
      v[i] = xr[t + i * 256];
      m = fmaxf(m, fmaxf(fmaxf(fabsf(v[i].x), fabsf(v[i].y)),
                         fmaxf(fabsf(v[i].z), fabsf(v[i].w))));
    }
#pragma unroll
    for (int o = 32; o > 0; o >>= 1) m = fmaxf(m, __shfl_xor(m, o));
    __shared__ float red[4];
    if ((t & 63) == 0) red[t >> 6] = m;
    __syncthreads();
    m = fmaxf(fmaxf(red[0], red[1]), fmaxf(red[2], red[3]));
    const float gamma = fmaxf(m, EPS_G);
    if (t == 0) gamma_out[b] = gamma;
    const float inv = QB / gamma;
    char4* xqr = (char4*)(xq + (size_t)b * KD);
#pragma unroll
    for (int i = 0; i < 4; ++i) {
      char4 q;
      q.x = (signed char)(int)fminf(fmaxf(rintf(v[i].x * inv), -QB), QB);
      q.y = (signed char)(int)fminf(fmaxf(rintf(v[i].y * inv), -QB), QB);
      q.z = (signed char)(int)fminf(fmaxf(rintf(v[i].z * inv), -QB), QB);
      q.w = (signed char)(int)fminf(fmaxf(rintf(v[i].w * inv), -QB), QB);
      xqr[t + i * 256] = q;
    }
  } else {
    const int row = b - M;
    const float4* wr_ = (const float4*)(w + (size_t)row * KD);
    char4* wqr = (char4*)(wq + (size_t)row * KD);
#pragma unroll
    for (int i = 0; i < 4; ++i) {
      const float4 v = wr_[t + i * 256];
      char4 q;
      q.x = (signed char)(int)v.x;
      q.y = (signed char)(int)v.y;
      q.z = (signed char)(int)v.z;
      q.w = (signed char)(int)v.w;
      wqr[t + i * 256] = q;
    }
  }
}

// ---------------------------------------------------------------------------
// 256x256 8-phase i8 GEMM. 512 thr = 8 waves (2M x 4N), per-wave out 128x64.
// BK=128 i8. LDS 128 KiB: A[2][256][128] | B[2][256][128], XOR-swizzled
// col ^= (row&7)<<4; pre-swizzled global source + swizzled asm ds_read;
// global_load_lds dest linear. Counted vmcnt(4) at ph4/ph8 only.
// ds_read balance 8/4/8/4: B-pair-0 of each tile prefetched in the previous
// ph4/ph8 AFTER the vmcnt(4)+barrier (its staging is in that drain set),
// issued before the MFMA cluster so latency hides under 16 MFMAs.
// ---------------------------------------------------------------------------
__global__ __launch_bounds__(512, 2) void gemm_i8_8ph_kernel(
    const signed char* __restrict__ A,   // [M][K] int8 activations
    const signed char* __restrict__ B,   // [N][K] int8 ternary weights
    const float* __restrict__ gamma,     // [M]
    const float* __restrict__ scale_p,   // [1]
    float* __restrict__ C) {             // [M][N] fp32
  extern __shared__ signed char lds[];
  signed char* ldsA = lds;           // 2 x 32768
  signed char* ldsB = lds + 65536;   // 2 x 32768

  const int t = threadIdx.x;
  const int lane = t & 63;
  const int wave = t >> 6;
  const int wr = wave >> 2;          // 0..1  M-half of tile
  const int wcol = wave & 3;         // 0..3  N-quarter of tile
  const int lr = lane & 15;
  const int lc = (lane >> 4) << 4;   // frag byte-col slot
  const int swzm = (lr & 7) << 4;    // read-side swizzle

  // XCD-aware bijective swizzle (512 blocks, 512 % 8 == 0)
  const int bid = blockIdx.x;
  const int swz = (bid & 7) * 64 + (bid >> 3);
  const int brow = (swz >> 4) * BM;  // 32 row-tiles
  const int bcol = (swz & 15) * BN;  // 16 col-tiles

  // Staging: chunk c -> (row_in_half = c>>3, slot = c&7); global col
  // pre-swizzled by the same involution the reader applies.
  const int c0 = t, c1 = t + 512;
  const int r0 = c0 >> 3, r1 = c1 >> 3;
  const int g0 = ((c0 & 7) << 4) ^ ((r0 & 7) << 4);
  const int g1 = ((c1 & 7) << 4) ^ ((r1 & 7) << 4);
  const signed char* sA0 = A + (size_t)(brow + r0) * KD + g0;
  const signed char* sA1 = A + (size_t)(brow + r1) * KD + g1;
  const signed char* sB0 = B + (size_t)(bcol + r0) * KD + g0;
  const signed char* sB1 = B + (size_t)(bcol + r1) * KD + g1;

  // LDS byte-offset bases for asm ds_read (dynamic-LDS aperture offset)
  const uint32_t lds0 =
      (uint32_t)(uintptr_t)(__attribute__((address_space(3))) void*)lds;
  const uint32_t aA0 = lds0 + (uint32_t)((wr * 128 + lr) * 128 + ((0 + lc) ^ swzm));
  const uint32_t aA1 = lds0 + (uint32_t)((wr * 128 + lr) * 128 + ((64 + lc) ^ swzm));
  const uint32_t aB0 = lds0 + 65536u +
      (uint32_t)((wcol * 64 + lr) * 128 + ((0 + lc) ^ swzm));
  const uint32_t aB1 = lds0 + 65536u +
      (uint32_t)((wcol * 64 + lr) * 128 + ((64 + lc) ^ swzm));

#define STAGE_A(d, h, kt)                                                      \
  do {                                                                         \
    GLOAD16(sA0 + (size_t)(h) * 128 * KD + (kt) * BKB,                         \
            ldsA + (d) * 32768 + (h) * 16384 + c0 * 16);                       \
    GLOAD16(sA1 + (size_t)(h) * 128 * KD + (kt) * BKB,                         \
            ldsA + (d) * 32768 + (h) * 16384 + c1 * 16);                       \
  } while (0)
#define STAGE_B(d, h, kt)                                                      \
  do {                                                                         \
    GLOAD16(sB0 + (size_t)(h) * 128 * KD + (kt) * BKB,                         \
            ldsB + (d) * 32768 + (h) * 16384 + c0 * 16);                       \
    GLOAD16(sB1 + (size_t)(h) * 128 * KD + (kt) * BKB,                         \
            ldsB + (d) * 32768 + (h) * 16384 + c1 * 16);                       \
  } while (0)

#define LDA_H(d, mh)                                                           \
  _Pragma("unroll") for (int m_ = 0; m_ < 4; ++m_) {                           \
    DSR(af[m_][0], aA0 + (d) * 32768u + (mh) * 8192u + m_ * 2048u);            \
    DSR(af[m_][1], aA1 + (d) * 32768u + (mh) * 8192u + m_ * 2048u);            \
  }
#define LDB_P(d, nh)                                                           \
  _Pragma("unroll") for (int n_ = 0; n_ < 2; ++n_) {                           \
    DSR(bf[(nh) * 2 + n_][0], aB0 + (d) * 32768u + (nh) * 4096u + n_ * 2048u); \
    DSR(bf[(nh) * 2 + n_][1], aB1 + (d) * 32768u + (nh) * 4096u + n_ * 2048u); \
  }

#define MFMA_Q(mh, nh)                                                         \
  do {                                                                         \
    __builtin_amdgcn_s_setprio(1);                                             \
    _Pragma("unroll") for (int m_ = 0; m_ < 4; ++m_)                           \
    _Pragma("unroll") for (int n_ = 0; n_ < 2; ++n_)                           \
    _Pragma("unroll") for (int k_ = 0; k_ < 2; ++k_)                           \
      acc[(mh) * 4 + m_][(nh) * 2 + n_] = __builtin_amdgcn_mfma_i32_16x16x64_i8( \
          af[m_][k_], bf[(nh) * 2 + n_][k_], acc[(mh) * 4 + m_][(nh) * 2 + n_], \
          0, 0, 0);                                                            \
    __builtin_amdgcn_s_setprio(0);                                             \
  } while (0)

  v4i acc[8][4];
#pragma unroll
  for (int i = 0; i < 8; ++i)
#pragma unroll
    for (int j = 0; j < 4; ++j) acc[i][j] = (v4i){0, 0, 0, 0};
  v4i af[4][2], bf[4][2];

  // Prologue: tile0 (4 halves, oldest) + tile1 B halves; wait tile0 landed;
  // then prefetch tile0's B-pair-0 fragments.
  STAGE_B(0, 0, 0); STAGE_B(0, 1, 0); STAGE_A(0, 0, 0); STAGE_A(0, 1, 0);
  STAGE_B(1, 0, 1); STAGE_B(1, 1, 1);
  WVM4;
  BAR; SB0;
  LDB_P(0, 0);

#pragma unroll 1
  for (int i = 0; i < NI; ++i) {
    const int kc1 = 2 * i + 1;            // buf1 tile (A halves staged ph1-2)
    const int kn2 = (2 * i + 2) & (NT - 1);
    const int kn3 = (2 * i + 3) & (NT - 1);

    // ---- K-tile 2i from buf0 ----  (ds_read per phase: 8/4/8/4)
    LDA_H(0, 0); STAGE_A(1, 0, kc1);
    BAR; WLG0; SB0; MFMA_Q(0, 0); SB0; BAR; SB0;      // ph1

    LDB_P(0, 1); STAGE_A(1, 1, kc1);
    BAR; WLG0; SB0; MFMA_Q(0, 1); SB0; BAR; SB0;      // ph2

    LDA_H(0, 1); STAGE_B(0, 0, kn2);
    BAR; WLG0; SB0; MFMA_Q(1, 0); SB0; BAR; SB0;      // ph3

    STAGE_B(0, 1, kn2); WVM4;
    BAR; SB0; LDB_P(1, 0); MFMA_Q(1, 1); SB0; BAR; SB0;  // ph4 (tile 2i+1 ready)

    // ---- K-tile 2i+1 from buf1 ----
    LDA_H(1, 0); STAGE_A(0, 0, kn2);
    BAR; WLG0; SB0; MFMA_Q(0, 0); SB0; BAR; SB0;      // ph5

    LDB_P(1, 1); STAGE_A(0, 1, kn2);
    BAR; WLG0; SB0; MFMA_Q(0, 1); SB0; BAR; SB0;      // ph6

    LDA_H(1, 1); STAGE_B(1, 0, kn3);
    BAR; WLG0; SB0; MFMA_Q(1, 0); SB0; BAR; SB0;      // ph7

    STAGE_B(1, 1, kn3); WVM4;
    BAR; SB0; LDB_P(0, 0); MFMA_Q(1, 1); SB0; BAR; SB0;  // ph8 (tile 2i+2 ready)
  }

  // Epilogue: out = (acc * (gamma/QB)) * scale, nontemporal (no re-read).
  const float scl = *scale_p;
  const int ccol0 = bcol + wcol * 64 + lr;
  const int crow0 = brow + wr * 128 + (lane >> 4) * 4;
#pragma unroll
  for (int m_ = 0; m_ < 8; ++m_) {
#pragma unroll
    for (int j = 0; j < 4; ++j) {
      const int row = crow0 + m_ * 16 + j;
      const float g = gamma[row] / QB;
#pragma unroll
      for (int n_ = 0; n_ < 4; ++n_) {
        __builtin_nontemporal_store(((float)acc[m_][n_][j] * g) * scl,
                                    &C[(size_t)row * ND + ccol0 + n_ * 16]);
      }
    }
  }
#undef STAGE_A
#undef STAGE_B
#undef LDA_H
#undef LDB_P
#undef MFMA_Q
}

// ---------------------------------------------------------------------------
extern "C" void kernel_launch(void* const* d_in, const int* in_sizes, int n_in,
                              void* d_out, int out_size, void* d_ws, size_t ws_size,
                              hipStream_t stream) {
  const float* x = (const float*)d_in[0];      // [M, K] = [8192, 4096]
  const float* w = (const float*)d_in[1];      // [N, K] = [4096, 4096]
  const float* scale = (const float*)d_in[2];  // [1]
  float* out = (float*)d_out;                  // [M, N]

  const int M = in_sizes[0] / KD;  // 8192

  // Workspace: wq [N*K] i8 | xq [M*K] i8 | gamma [M] f32
  signed char* wq = (signed char*)d_ws;
  signed char* xq = wq + (size_t)ND * KD;
  float* gamma = (float*)(xq + (size_t)M * KD);

  quant_fused_kernel<<<M + ND, 256, 0, stream>>>(x, w, xq, wq, gamma, M);

  const int nwg = (M / BM) * (ND / BN);  // 32*16 = 512
  gemm_i8_8ph_kernel<<<nwg, 512, 131072, stream>>>(xq, wq, gamma, scale, out);
}

// Round 7
// 380.524 us; speedup vs baseline: 1.2040x; 1.2040x over previous
//
#include <hip/hip_runtime.h>
#include <hip/hip_bf16.h>
#include <stdint.h>

#define QB 127.0f
#define EPS_G 1e-5f
#define KD 4096
#define ND 4096
#define BM 256
#define BN 256
#define BKB 128           // K-bytes (= i8 elements) per K-tile
#define NT (KD / BKB)     // 32 K-tiles
#define NI (NT / 2)       // 16 iterations, 2 K-tiles each

typedef int v4i __attribute__((ext_vector_type(4)));

#define GLOAD16(gp, lp)                                                        \
  __builtin_amdgcn_global_load_lds(                                            \
      (const __attribute__((address_space(1))) void*)(gp),                     \
      (__attribute__((address_space(3))) void*)(lp), 16, 0, 0)

#define BAR  __builtin_amdgcn_s_barrier()
// Staging-drain fence: asm volatile + "memory" also stops the compiler from
// hoisting any LDS read above this point (buffer-ready guarantee).
#define WVM4 asm volatile("s_waitcnt vmcnt(4)" ::: "memory")

// ---------------------------------------------------------------------------
// Fused quant: blocks [0,M) quantize x rows (absmax int8); blocks [M,M+N)
// convert w rows {-1,0,1} fp32 -> i8. One row of 4096 per 256-thread block.
// ---------------------------------------------------------------------------
__global__ __launch_bounds__(256) void quant_fused_kernel(
    const float* __restrict__ x, const float* __restrict__ w,
    signed char* __restrict__ xq, signed char* __restrict__ wq,
    float* __restrict__ gamma_out, int M) {
  const int b = blockIdx.x;
  const int t = threadIdx.x;
  if (b < M) {
    const float4* xr = (const float4*)(x + (size_t)b * KD);
    float4 v[4];
    float m = 0.f;
#pragma unroll
    for (int i = 0; i < 4; ++i) {
      v[i] = xr[t + i * 256];
      m = fmaxf(m, fmaxf(fmaxf(fabsf(v[i].x), fabsf(v[i].y)),
                         fmaxf(fabsf(v[i].z), fabsf(v[i].w))));
    }
#pragma unroll
    for (int o = 32; o > 0; o >>= 1) m = fmaxf(m, __shfl_xor(m, o));
    __shared__ float red[4];
    if ((t & 63) == 0) red[t >> 6] = m;
    __syncthreads();
    m = fmaxf(fmaxf(red[0], red[1]), fmaxf(red[2], red[3]));
    const float gamma = fmaxf(m, EPS_G);
    if (t == 0) gamma_out[b] = gamma;
    const float inv = QB / gamma;
    char4* xqr = (char4*)(xq + (size_t)b * KD);
#pragma unroll
    for (int i = 0; i < 4; ++i) {
      char4 q;
      q.x = (signed char)(int)fminf(fmaxf(rintf(v[i].x * inv), -QB), QB);
      q.y = (signed char)(int)fminf(fmaxf(rintf(v[i].y * inv), -QB), QB);
      q.z = (signed char)(int)fminf(fmaxf(rintf(v[i].z * inv), -QB), QB);
      q.w = (signed char)(int)fminf(fmaxf(rintf(v[i].w * inv), -QB), QB);
      xqr[t + i * 256] = q;
    }
  } else {
    const int row = b - M;
    const float4* wr_ = (const float4*)(w + (size_t)row * KD);
    char4* wqr = (char4*)(wq + (size_t)row * KD);
#pragma unroll
    for (int i = 0; i < 4; ++i) {
      const float4 v = wr_[t + i * 256];
      char4 q;
      q.x = (signed char)(int)v.x;
      q.y = (signed char)(int)v.y;
      q.z = (signed char)(int)v.z;
      q.w = (signed char)(int)v.w;
      wqr[t + i * 256] = q;
    }
  }
}

// ---------------------------------------------------------------------------
// 256x256 8-phase i8 GEMM. 512 thr = 8 waves (2M x 4N), per-wave out 128x64.
// BK=128 i8. LDS 128 KiB: A[2][256][128] | B[2][256][128], XOR-swizzled
// col ^= (row&7)<<4; pre-swizzled global source + swizzled C++ ds_read;
// global_load_lds dest linear. Counted vmcnt(4) at ph4/ph8 only.
//
// r5 change vs r3 (146us): (1) NO hard lgkmcnt(0)/sched_barrier around the
// MFMA cluster -- C++ LDS loads let the compiler emit per-use fine-grained
// lgkmcnt(N), so each wave's first MFMA starts after only ITS fragments
// arrive and the LDS-read tail completes under the MFMA cluster (intra-phase
// LDS/MFMA pipe overlap; r3 serialized them: 576+653 cyc/phase).
// (2) ds_read balance 8/4/8/4: B-pair-0 of each tile prefetched in the
// preceding ph4/ph8 AFTER WVM4+BAR (its staging is in that drain set).
// Barrier count, vmcnt ledger, stage order: identical to the passing r3/r4.
// ---------------------------------------------------------------------------
__global__ __launch_bounds__(512, 2) void gemm_i8_8ph_kernel(
    const signed char* __restrict__ A,   // [M][K] int8 activations
    const signed char* __restrict__ B,   // [N][K] int8 ternary weights
    const float* __restrict__ gamma,     // [M]
    const float* __restrict__ scale_p,   // [1]
    float* __restrict__ C) {             // [M][N] fp32
  extern __shared__ signed char lds[];
  signed char* ldsA = lds;           // 2 x 32768
  signed char* ldsB = lds + 65536;   // 2 x 32768

  const int t = threadIdx.x;
  const int lane = t & 63;
  const int wave = t >> 6;
  const int wr = wave >> 2;          // 0..1  M-half of tile
  const int wcol = wave & 3;         // 0..3  N-quarter of tile
  const int lr = lane & 15;
  const int lc = (lane >> 4) << 4;   // frag byte-col slot
  const int swzm = (lr & 7) << 4;    // read-side swizzle

  // XCD-aware bijective swizzle (512 blocks, 512 % 8 == 0)
  const int bid = blockIdx.x;
  const int swz = (bid & 7) * 64 + (bid >> 3);
  const int brow = (swz >> 4) * BM;  // 32 row-tiles
  const int bcol = (swz & 15) * BN;  // 16 col-tiles

  // Staging: chunk c -> (row_in_half = c>>3, slot = c&7); global col
  // pre-swizzled by the same involution the reader applies.
  const int c0 = t, c1 = t + 512;
  const int r0 = c0 >> 3, r1 = c1 >> 3;
  const int g0 = ((c0 & 7) << 4) ^ ((r0 & 7) << 4);
  const int g1 = ((c1 & 7) << 4) ^ ((r1 & 7) << 4);
  const signed char* sA0 = A + (size_t)(brow + r0) * KD + g0;
  const signed char* sA1 = A + (size_t)(brow + r1) * KD + g1;
  const signed char* sB0 = B + (size_t)(bcol + r0) * KD + g0;
  const signed char* sB1 = B + (size_t)(bcol + r1) * KD + g1;

#define STAGE_A(d, h, kt)                                                      \
  do {                                                                         \
    GLOAD16(sA0 + (size_t)(h) * 128 * KD + (kt) * BKB,                         \
            ldsA + (d) * 32768 + (h) * 16384 + c0 * 16);                       \
    GLOAD16(sA1 + (size_t)(h) * 128 * KD + (kt) * BKB,                         \
            ldsA + (d) * 32768 + (h) * 16384 + c1 * 16);                       \
  } while (0)
#define STAGE_B(d, h, kt)                                                      \
  do {                                                                         \
    GLOAD16(sB0 + (size_t)(h) * 128 * KD + (kt) * BKB,                         \
            ldsB + (d) * 32768 + (h) * 16384 + c0 * 16);                       \
    GLOAD16(sB1 + (size_t)(h) * 128 * KD + (kt) * BKB,                         \
            ldsB + (d) * 32768 + (h) * 16384 + c1 * 16);                       \
  } while (0)

#define LDA_H(d, mh)                                                           \
  _Pragma("unroll") for (int m_ = 0; m_ < 4; ++m_)                             \
  _Pragma("unroll") for (int k_ = 0; k_ < 2; ++k_)                             \
    af[m_][k_] = *(const v4i*)(ldsA + (d) * 32768 +                            \
        (wr * 128 + (mh) * 64 + m_ * 16 + lr) * 128 + ((k_ * 64 + lc) ^ swzm))
#define LDB_P(d, nh)                                                           \
  _Pragma("unroll") for (int n_ = 0; n_ < 2; ++n_)                             \
  _Pragma("unroll") for (int k_ = 0; k_ < 2; ++k_)                             \
    bf[(nh) * 2 + n_][k_] = *(const v4i*)(ldsB + (d) * 32768 +                 \
        (wcol * 64 + (nh) * 32 + n_ * 16 + lr) * 128 + ((k_ * 64 + lc) ^ swzm))

#define MFMA_Q(mh, nh)                                                         \
  do {                                                                         \
    __builtin_amdgcn_s_setprio(1);                                             \
    _Pragma("unroll") for (int m_ = 0; m_ < 4; ++m_)                           \
    _Pragma("unroll") for (int n_ = 0; n_ < 2; ++n_)                           \
    _Pragma("unroll") for (int k_ = 0; k_ < 2; ++k_)                           \
      acc[(mh) * 4 + m_][(nh) * 2 + n_] = __builtin_amdgcn_mfma_i32_16x16x64_i8( \
          af[m_][k_], bf[(nh) * 2 + n_][k_], acc[(mh) * 4 + m_][(nh) * 2 + n_], \
          0, 0, 0);                                                            \
    __builtin_amdgcn_s_setprio(0);                                             \
  } while (0)

  v4i acc[8][4];
#pragma unroll
  for (int i = 0; i < 8; ++i)
#pragma unroll
    for (int j = 0; j < 4; ++j) acc[i][j] = (v4i){0, 0, 0, 0};
  v4i af[4][2], bf[4][2];

  // Prologue: tile0 (4 halves, oldest) + tile1 B halves; wait tile0 landed;
  // then prefetch tile0's B-pair-0 fragments.
  STAGE_B(0, 0, 0); STAGE_B(0, 1, 0); STAGE_A(0, 0, 0); STAGE_A(0, 1, 0);
  STAGE_B(1, 0, 1); STAGE_B(1, 1, 1);
  WVM4;
  BAR;
  LDB_P(0, 0);

#pragma unroll 1
  for (int i = 0; i < NI; ++i) {
    const int kc1 = 2 * i + 1;            // buf1 tile (A halves staged ph1-2)
    const int kn2 = (2 * i + 2) & (NT - 1);
    const int kn3 = (2 * i + 3) & (NT - 1);

    // ---- K-tile 2i from buf0 ----  (ds_read per phase: 8/4/8/4)
    LDA_H(0, 0); STAGE_A(1, 0, kc1);
    BAR; MFMA_Q(0, 0); BAR;                            // ph1

    LDB_P(0, 1); STAGE_A(1, 1, kc1);
    BAR; MFMA_Q(0, 1); BAR;                            // ph2

    LDA_H(0, 1); STAGE_B(0, 0, kn2);
    BAR; MFMA_Q(1, 0); BAR;                            // ph3

    STAGE_B(0, 1, kn2); WVM4;
    BAR; LDB_P(1, 0); MFMA_Q(1, 1); BAR;               // ph4 (tile 2i+1 ready)

    // ---- K-tile 2i+1 from buf1 ----
    LDA_H(1, 0); STAGE_A(0, 0, kn2);
    BAR; MFMA_Q(0, 0); BAR;                            // ph5

    LDB_P(1, 1); STAGE_A(0, 1, kn2);
    BAR; MFMA_Q(0, 1); BAR;                            // ph6

    LDA_H(1, 1); STAGE_B(1, 0, kn3);
    BAR; MFMA_Q(1, 0); BAR;                            // ph7

    STAGE_B(1, 1, kn3); WVM4;
    BAR; LDB_P(0, 0); MFMA_Q(1, 1); BAR;               // ph8 (tile 2i+2 ready)
  }

  // Epilogue: out = (acc * (gamma/QB)) * scale, nontemporal (no re-read).
  const float scl = *scale_p;
  const int ccol0 = bcol + wcol * 64 + lr;
  const int crow0 = brow + wr * 128 + (lane >> 4) * 4;
#pragma unroll
  for (int m_ = 0; m_ < 8; ++m_) {
#pragma unroll
    for (int j = 0; j < 4; ++j) {
      const int row = crow0 + m_ * 16 + j;
      const float g = gamma[row] / QB;
#pragma unroll
      for (int n_ = 0; n_ < 4; ++n_) {
        __builtin_nontemporal_store(((float)acc[m_][n_][j] * g) * scl,
                                    &C[(size_t)row * ND + ccol0 + n_ * 16]);
      }
    }
  }
#undef STAGE_A
#undef STAGE_B
#undef LDA_H
#undef LDB_P
#undef MFMA_Q
}

// ---------------------------------------------------------------------------
extern "C" void kernel_launch(void* const* d_in, const int* in_sizes, int n_in,
                              void* d_out, int out_size, void* d_ws, size_t ws_size,
                              hipStream_t stream) {
  const float* x = (const float*)d_in[0];      // [M, K] = [8192, 4096]
  const float* w = (const float*)d_in[1];      // [N, K] = [4096, 4096]
  const float* scale = (const float*)d_in[2];  // [1]
  float* out = (float*)d_out;                  // [M, N]

  const int M = in_sizes[0] / KD;  // 8192

  // Workspace: wq [N*K] i8 | xq [M*K] i8 | gamma [M] f32
  signed char* wq = (signed char*)d_ws;
  signed char* xq = wq + (size_t)ND * KD;
  float* gamma = (float*)(xq + (size_t)M * KD);

  quant_fused_kernel<<<M + ND, 256, 0, stream>>>(x, w, xq, wq, gamma, M);

  const int nwg = (M / BM) * (ND / BN);  // 32*16 = 512
  gemm_i8_8ph_kernel<<<nwg, 512, 131072, stream>>>(xq, wq, gamma, scale, out);
}

// Round 11
// 379.431 us; speedup vs baseline: 1.2075x; 1.0029x over previous
//
#include <hip/hip_runtime.h>
#include <hip/hip_bf16.h>
#include <stdint.h>

#define QB 127.0f
#define EPS_G 1e-5f
#define KD 4096
#define ND 4096
#define BM 256
#define BN 256
#define BKB 128           // K-bytes (= i8 elements) per K-tile
#define NT (KD / BKB)     // 32 K-tiles

typedef int v4i __attribute__((ext_vector_type(4)));

#define GLOAD16(gp, lp)                                                        \
  __builtin_amdgcn_global_load_lds(                                            \
      (const __attribute__((address_space(1))) void*)(gp),                     \
      (__attribute__((address_space(3))) void*)(lp), 16, 0, 0)

// ---------------------------------------------------------------------------
// Fused quant: blocks [0,M) quantize x rows (absmax int8); blocks [M,M+N)
// convert w rows {-1,0,1} fp32 -> i8. One row of 4096 per 256-thread block.
// ---------------------------------------------------------------------------
__global__ __launch_bounds__(256) void quant_fused_kernel(
    const float* __restrict__ x, const float* __restrict__ w,
    signed char* __restrict__ xq, signed char* __restrict__ wq,
    float* __restrict__ gamma_out, int M) {
  const int b = blockIdx.x;
  const int t = threadIdx.x;
  if (b < M) {
    const float4* xr = (const float4*)(x + (size_t)b * KD);
    float4 v[4];
    float m = 0.f;
#pragma unroll
    for (int i = 0; i < 4; ++i) {
      v[i] = xr[t + i * 256];
      m = fmaxf(m, fmaxf(fmaxf(fabsf(v[i].x), fabsf(v[i].y)),
                         fmaxf(fabsf(v[i].z), fabsf(v[i].w))));
    }
#pragma unroll
    for (int o = 32; o > 0; o >>= 1) m = fmaxf(m, __shfl_xor(m, o));
    __shared__ float red[4];
    if ((t & 63) == 0) red[t >> 6] = m;
    __syncthreads();
    m = fmaxf(fmaxf(red[0], red[1]), fmaxf(red[2], red[3]));
    const float gamma = fmaxf(m, EPS_G);
    if (t == 0) gamma_out[b] = gamma;
    const float inv = QB / gamma;
    char4* xqr = (char4*)(xq + (size_t)b * KD);
#pragma unroll
    for (int i = 0; i < 4; ++i) {
      char4 q;
      q.x = (signed char)(int)fminf(fmaxf(rintf(v[i].x * inv), -QB), QB);
      q.y = (signed char)(int)fminf(fmaxf(rintf(v[i].y * inv), -QB), QB);
      q.z = (signed char)(int)fminf(fmaxf(rintf(v[i].z * inv), -QB), QB);
      q.w = (signed char)(int)fminf(fmaxf(rintf(v[i].w * inv), -QB), QB);
      xqr[t + i * 256] = q;
    }
  } else {
    const int row = b - M;
    const float4* wr_ = (const float4*)(w + (size_t)row * KD);
    char4* wqr = (char4*)(wq + (size_t)row * KD);
#pragma unroll
    for (int i = 0; i < 4; ++i) {
      const float4 v = wr_[t + i * 256];
      char4 q;
      q.x = (signed char)(int)v.x;
      q.y = (signed char)(int)v.y;
      q.z = (signed char)(int)v.z;
      q.w = (signed char)(int)v.w;
      wqr[t + i * 256] = q;
    }
  }
}

// ---------------------------------------------------------------------------
// 256x256 i8 GEMM, ONE big phase per K-tile (r8). 512 thr = 8 waves (2Mx4N),
// per-wave out 128x64. BK=128. LDS 128 KiB double-buffered, XOR-swizzle
// col ^= (row&7)<<4 (pre-swizzled global source + swizzled C++ ds_read;
// global_load_lds dest linear).
//
// r7 falsified intra-phase wait theory: Occupancy 20.6% => 1 block/CU
// (LDS 128K > 80K), so all 8 waves share one barrier rhythm and the 8-phase
// barriers SERIALIZE the LDS pipe (2259 cyc/K-tile) against the MFMA pipe
// (2611 cyc/K-tile): observed 5324 cyc/K-tile = sum. Fix: no barriers inside
// a K-tile. Per K-tile: STAGE(next, 8 gloads) -> 24 ds_reads + 64 MFMA with
// compiler per-use lgkmcnt -> __syncthreads() (vmcnt0 drain is ~free: body
// ~2800 cyc >> 900 cyc HBM latency; m97-proven race-safe structure). Waves
// drift within the body so LDS streaming overlaps MFMA: wall -> max ~2771.
// ---------------------------------------------------------------------------
__global__ __launch_bounds__(512, 2) void gemm_i8_1ph_kernel(
    const signed char* __restrict__ A,   // [M][K] int8 activations
    const signed char* __restrict__ B,   // [N][K] int8 ternary weights
    const float* __restrict__ gamma,     // [M]
    const float* __restrict__ scale_p,   // [1]
    float* __restrict__ C) {             // [M][N] fp32
  extern __shared__ signed char lds[];
  signed char* ldsA = lds;           // 2 x 32768
  signed char* ldsB = lds + 65536;   // 2 x 32768

  const int t = threadIdx.x;
  const int lane = t & 63;
  const int wave = t >> 6;
  const int wr = wave >> 2;          // 0..1  M-half of tile
  const int wcol = wave & 3;         // 0..3  N-quarter of tile
  const int lr = lane & 15;
  const int lc = (lane >> 4) << 4;   // frag byte-col slot
  const int swzm = (lr & 7) << 4;    // read-side swizzle

  // XCD-aware bijective swizzle (512 blocks, 512 % 8 == 0)
  const int bid = blockIdx.x;
  const int swz = (bid & 7) * 64 + (bid >> 3);
  const int brow = (swz >> 4) * BM;  // 32 row-tiles
  const int bcol = (swz & 15) * BN;  // 16 col-tiles

  // Staging: chunk c -> (row_in_half = c>>3, slot = c&7); global col
  // pre-swizzled by the same involution the reader applies.
  const int c0 = t, c1 = t + 512;
  const int r0 = c0 >> 3, r1 = c1 >> 3;
  const int g0 = ((c0 & 7) << 4) ^ ((r0 & 7) << 4);
  const int g1 = ((c1 & 7) << 4) ^ ((r1 & 7) << 4);
  const signed char* sA0 = A + (size_t)(brow + r0) * KD + g0;
  const signed char* sA1 = A + (size_t)(brow + r1) * KD + g1;
  const signed char* sB0 = B + (size_t)(bcol + r0) * KD + g0;
  const signed char* sB1 = B + (size_t)(bcol + r1) * KD + g1;

#define STAGE_A(d, h, kt)                                                      \
  do {                                                                         \
    GLOAD16(sA0 + (size_t)(h) * 128 * KD + (kt) * BKB,                         \
            ldsA + (d) * 32768 + (h) * 16384 + c0 * 16);                       \
    GLOAD16(sA1 + (size_t)(h) * 128 * KD + (kt) * BKB,                         \
            ldsA + (d) * 32768 + (h) * 16384 + c1 * 16);                       \
  } while (0)
#define STAGE_B(d, h, kt)                                                      \
  do {                                                                         \
    GLOAD16(sB0 + (size_t)(h) * 128 * KD + (kt) * BKB,                         \
            ldsB + (d) * 32768 + (h) * 16384 + c0 * 16);                       \
    GLOAD16(sB1 + (size_t)(h) * 128 * KD + (kt) * BKB,                         \
            ldsB + (d) * 32768 + (h) * 16384 + c1 * 16);                       \
  } while (0)

  v4i acc[8][4];
#pragma unroll
  for (int i = 0; i < 8; ++i)
#pragma unroll
    for (int j = 0; j < 4; ++j) acc[i][j] = (v4i){0, 0, 0, 0};

  // Prologue: stage tile 0 into buf0, drain, barrier.
  STAGE_A(0, 0, 0); STAGE_A(0, 1, 0);
  STAGE_B(0, 0, 0); STAGE_B(0, 1, 0);
  __syncthreads();

#pragma unroll 1
  for (int kt = 0; kt < NT; ++kt) {
    const int tn = (kt + 1) & (NT - 1);  // last iter re-stages tile 0 (unused)
    const int dn = (kt + 1) & 1;
    const int dc = kt & 1;

    // Stage next K-tile into the other buffer (lands by end-of-iter drain).
    STAGE_A(dn, 0, tn); STAGE_A(dn, 1, tn);
    STAGE_B(dn, 0, tn); STAGE_B(dn, 1, tn);

    // Compute current K-tile: no internal barriers; compiler emits per-use
    // lgkmcnt so MFMAs start as fragments arrive; waves drift -> pipe overlap.
#pragma unroll
    for (int ks = 0; ks < 2; ++ks) {
      v4i af[8], bf[4];
#pragma unroll
      for (int m_ = 0; m_ < 8; ++m_)
        af[m_] = *(const v4i*)(ldsA + dc * 32768 +
            (wr * 128 + m_ * 16 + lr) * 128 + ((ks * 64 + lc) ^ swzm));
#pragma unroll
      for (int n_ = 0; n_ < 4; ++n_)
        bf[n_] = *(const v4i*)(ldsB + dc * 32768 +
            (wcol * 64 + n_ * 16 + lr) * 128 + ((ks * 64 + lc) ^ swzm));
      __builtin_amdgcn_s_setprio(1);
#pragma unroll
      for (int m_ = 0; m_ < 8; ++m_)
#pragma unroll
        for (int n_ = 0; n_ < 4; ++n_)
          acc[m_][n_] = __builtin_amdgcn_mfma_i32_16x16x64_i8(
              af[m_], bf[n_], acc[m_][n_], 0, 0, 0);
      __builtin_amdgcn_s_setprio(0);
    }

    // Drain staging (vmcnt0+lgkmcnt0) + barrier: next buffer ready, current
    // buffer free for overwrite. Body >> HBM latency -> drain ~free.
    __syncthreads();
  }

  // Epilogue: out = (acc * (gamma/QB)) * scale, nontemporal (no re-read).
  const float scl = *scale_p;
  const int ccol0 = bcol + wcol * 64 + lr;
  const int crow0 = brow + wr * 128 + (lane >> 4) * 4;
#pragma unroll
  for (int m_ = 0; m_ < 8; ++m_) {
#pragma unroll
    for (int j = 0; j < 4; ++j) {
      const int row = crow0 + m_ * 16 + j;
      const float g = gamma[row] / QB;
#pragma unroll
      for (int n_ = 0; n_ < 4; ++n_) {
        __builtin_nontemporal_store(((float)acc[m_][n_][j] * g) * scl,
                                    &C[(size_t)row * ND + ccol0 + n_ * 16]);
      }
    }
  }
#undef STAGE_A
#undef STAGE_B
}

// ---------------------------------------------------------------------------
extern "C" void kernel_launch(void* const* d_in, const int* in_sizes, int n_in,
                              void* d_out, int out_size, void* d_ws, size_t ws_size,
                              hipStream_t stream) {
  const float* x = (const float*)d_in[0];      // [M, K] = [8192, 4096]
  const float* w = (const float*)d_in[1];      // [N, K] = [4096, 4096]
  const float* scale = (const float*)d_in[2];  // [1]
  float* out = (float*)d_out;                  // [M, N]

  const int M = in_sizes[0] / KD;  // 8192

  // Workspace: wq [N*K] i8 | xq [M*K] i8 | gamma [M] f32
  signed char* wq = (signed char*)d_ws;
  signed char* xq = wq + (size_t)ND * KD;
  float* gamma = (float*)(xq + (size_t)M * KD);

  quant_fused_kernel<<<M + ND, 256, 0, stream>>>(x, w, xq, wq, gamma, M);

  const int nwg = (M / BM) * (ND / BN);  // 32*16 = 512
  gemm_i8_1ph_kernel<<<nwg, 512, 131072, stream>>>(xq, wq, gamma, scale, out);
}